// Round 15
// baseline (739.073 us; speedup 1.0000x reference)
//
#include <hip/hip_runtime.h>
#include <cstdint>
#include <cstddef>

typedef _Float16 hf;
typedef _Float16 h8v __attribute__((ext_vector_type(8)));
typedef float f4v __attribute__((ext_vector_type(4)));

#define NS 64
#define NO 256
#define MP 16384
#define KD 1024

__device__ __forceinline__ h8v cvt8(float4 a, float4 b) {
    h8v r;
    r[0] = (hf)a.x; r[1] = (hf)a.y; r[2] = (hf)a.z; r[3] = (hf)a.w;
    r[4] = (hf)b.x; r[5] = (hf)b.y; r[6] = (hf)b.z; r[7] = (hf)b.w;
    return r;
}
__device__ __forceinline__ float f4at(const float4& a, const float4& b, int e) {
    const float* p = e < 4 ? (const float*)&a : (const float*)&b;
    return p[e & 3];
}
// HBM -> LDS DMA, 16B per lane, linear dest (wave-uniform base + lane*16)
__device__ __forceinline__ void gl16(const hf* g, hf* l) {
    __builtin_amdgcn_global_load_lds(
        (const __attribute__((address_space(1))) void*)g,
        (__attribute__((address_space(3))) void*)l, 16, 0, 0);
}

// ---------------------------------------------------------------- fp32 -> fp16 pack
__global__ void k_pack16(const float* __restrict__ src, hf* __restrict__ dst, int n8) {
    int g = blockIdx.x * 256 + threadIdx.x;
    if (g >= n8) return;
    const float4* s4 = (const float4*)src;
    float4 a = s4[2 * g], b = s4[2 * g + 1];
    *(h8v*)(dst + (size_t)g * 8) = cvt8(a, b);
}

// ---------------------------------------------------------------- batched weight prep
struct RoR { const float* src; hf* dhi; hf* dlo; int Asrc; int aOff; };
struct RoRs { RoR r[7]; };
__global__ void k_reorder16b(RoRs RR) {
    const RoR rt = RR.r[blockIdx.z];
    __shared__ float tile[64][65];
    int c = blockIdx.x, a0 = blockIdx.y * 64;
    int t = threadIdx.x, lx = t & 63, ly = t >> 6;
#pragma unroll
    for (int p = 0; p < 16; ++p) {
        int ar = ly + p * 4;
        tile[ar][lx] = rt.src[(size_t)(c * rt.Asrc + rt.aOff + a0 + ar) * 64 + lx];
    }
    __syncthreads();
#pragma unroll
    for (int p = 0; p < 16; ++p) {
        int d = ly + p * 4;
        float v = tile[lx][d];
        hf h = (hf)v;
        size_t idx = (size_t)(c * 64 + d) * 1024 + a0 + lx;
        rt.dhi[idx] = h;
        if (rt.dlo) rt.dlo[idx] = (hf)(v - (float)h);
    }
}

struct TrR { const float* src; hf* dhi; hf* dlo; };
struct TrRs { TrR r[3]; };
__global__ void k_transpose16b(TrRs RR) {
    const TrR rt = RR.r[blockIdx.z];
    __shared__ float tile[64][65];
    int r0 = blockIdx.x * 64, s0 = blockIdx.y * 64;
    int t = threadIdx.x, lx = t & 63, ly = t >> 6;
#pragma unroll
    for (int p = 0; p < 16; ++p) {
        int srow = ly + p * 4;
        tile[srow][lx] = rt.src[(size_t)(s0 + srow) * 1024 + r0 + lx];
    }
    __syncthreads();
#pragma unroll
    for (int p = 0; p < 16; ++p) {
        int rr = ly + p * 4;
        float v = tile[lx][rr];
        hf h = (hf)v;
        size_t idx = (size_t)(r0 + rr) * 1024 + s0 + lx;
        rt.dhi[idx] = h;
        if (rt.dlo) rt.dlo[idx] = (hf)(v - (float)h);
    }
}

__global__ void k_prep_bc(const float* __restrict__ ab2, const float* __restrict__ ob2,
                          const float* __restrict__ sb2, const float* __restrict__ ab3,
                          const float* __restrict__ ob3, const float* __restrict__ sb3,
                          float* __restrict__ b2cat, float* __restrict__ b3a,
                          float* __restrict__ b3o, float* __restrict__ b3s) {
    int g = blockIdx.x * 256 + threadIdx.x;
    if (g >= 1024) return;
    b2cat[g] = ab2[g]; b2cat[1024 + g] = ob2[g]; b2cat[2048 + g] = sb2[g];
    float sa = 0.f, so = 0.f, ss = 0.f;
    for (int c = 0; c < 16; ++c) {
        sa += ab3[c * 1024 + g];
        so += ob3[c * 1024 + g];
        ss += sb3[c * 1024 + g];
    }
    b3a[g] = sa; b3o[g] = so; b3s[g] = ss;
}

__global__ void k_init_ho(const float* __restrict__ h, const float* __restrict__ o,
                          float* __restrict__ outbuf, hf* __restrict__ h16, hf* __restrict__ o16) {
    int g = blockIdx.x * 256 + threadIdx.x;
    if (g < NS * KD) { float v = h[g]; outbuf[g] = v; h16[g] = (hf)v; }
    int g2 = g - NS * KD;
    if (g2 >= 0 && g2 < NO * KD) { float v = o[g2]; outbuf[NS * KD + g2] = v; o16[g2] = (hf)v; }
}

// ---------------------------------------------------------------- prep GEMM (one-time)
// 128x128 tile, acc 4x4 (64 AGPR), gload_lds DMA staging, 24KB LDS -> high occupancy.
__global__ __launch_bounds__(256, 4) void k_prep_gemm(
    const hf* __restrict__ sp16,
    const hf* __restrict__ Wah, const hf* __restrict__ Wal,
    const hf* __restrict__ Wo2, const hf* __restrict__ Ws2,
    const float* __restrict__ b2cat,
    hf* __restrict__ Sh, hf* __restrict__ Sl,
    hf* __restrict__ So, hf* __restrict__ Ss) {
    __shared__ hf Ah[4096];
    __shared__ hf Bh[4096];
    __shared__ hf Bl[4096];
    const int tid = threadIdx.x;
    int lin = blockIdx.y * 24 + blockIdx.x;      // grid (24,128) = 3072, %8==0
    int xcd = lin & 7, slot = lin >> 3;          // slot 0..383
    int xn = slot % 24;
    const int m0 = ((xcd << 4) + slot / 24) * 128;
    const int plane = xn >> 3;                   // 0 att, 1 o2s, 2 s2o
    const int nbase = (xn & 7) * 128;
    const hf* Bb = plane == 0 ? Wah : (plane == 1 ? Wo2 : Ws2);
    const bool hasL = (plane == 0);
    const int lane = tid & 63, wid = tid >> 6;
    const int wm = wid >> 1, wn = wid & 1;
    const int lr = lane & 15, lg = lane >> 4;
    const int rsl = (lg ^ ((lr >> 1) & 3)) * 8;

    // DMA chunk geometry: lane l -> row (16*wid + (l>>2)), LDS slot (l&3);
    // inverse-swizzled global segment so slot s of row r holds seg s ^ ((r>>1)&3).
    const int crow = lane >> 2;
    const int gseg = ((lane & 3) ^ ((lane >> 3) & 3)) * 8;
    hf* ldsA0 = Ah + wid * 512;         hf* ldsA1 = Ah + 2048 + wid * 512;
    hf* ldsB0 = Bh + wid * 512;         hf* ldsB1 = Bh + 2048 + wid * 512;
    hf* ldsL0 = Bl + wid * 512;         hf* ldsL1 = Bl + 2048 + wid * 512;
    const hf* gA0 = sp16 + (size_t)(m0 +      wid * 16 + crow) * KD + gseg;
    const hf* gA1 = sp16 + (size_t)(m0 + 64 + wid * 16 + crow) * KD + gseg;
    const hf* gB0 = Bb  + (size_t)(nbase +      wid * 16 + crow) * KD + gseg;
    const hf* gB1 = Bb  + (size_t)(nbase + 64 + wid * 16 + crow) * KD + gseg;
    const hf* gL0 = Wal + (size_t)(nbase +      wid * 16 + crow) * KD + gseg;
    const hf* gL1 = Wal + (size_t)(nbase + 64 + wid * 16 + crow) * KD + gseg;

    f4v acc[4][4];
    f4v zz; zz[0] = 0.f; zz[1] = 0.f; zz[2] = 0.f; zz[3] = 0.f;
#pragma unroll
    for (int a = 0; a < 4; ++a)
#pragma unroll
        for (int b = 0; b < 4; ++b) acc[a][b] = zz;

    for (int t = 0; t < 32; ++t) {
        const int kk = t * 32;
        __syncthreads();                       // readers of previous tile done
        gl16(gA0 + kk, ldsA0); gl16(gA1 + kk, ldsA1);
        gl16(gB0 + kk, ldsB0); gl16(gB1 + kk, ldsB1);
        if (hasL) { gl16(gL0 + kk, ldsL0); gl16(gL1 + kk, ldsL1); }
        __syncthreads();                       // vmcnt drained before barrier
        h8v fa[4], fb[4];
#pragma unroll
        for (int x = 0; x < 4; ++x) {
            fa[x] = *(const h8v*)(Ah + (wm * 64 + x * 16 + lr) * 32 + rsl);
            fb[x] = *(const h8v*)(Bh + (wn * 64 + x * 16 + lr) * 32 + rsl);
        }
#pragma unroll
        for (int mi = 0; mi < 4; ++mi)
#pragma unroll
            for (int ni = 0; ni < 4; ++ni)
                acc[mi][ni] = __builtin_amdgcn_mfma_f32_16x16x32_f16(fa[mi], fb[ni], acc[mi][ni], 0, 0, 0);
        if (hasL) {
#pragma unroll
            for (int x = 0; x < 4; ++x)
                fb[x] = *(const h8v*)(Bl + (wn * 64 + x * 16 + lr) * 32 + rsl);
#pragma unroll
            for (int mi = 0; mi < 4; ++mi)
#pragma unroll
                for (int ni = 0; ni < 4; ++ni)
                    acc[mi][ni] = __builtin_amdgcn_mfma_f32_16x16x32_f16(fa[mi], fb[ni], acc[mi][ni], 0, 0, 0);
        }
    }
#pragma unroll
    for (int mi = 0; mi < 4; ++mi)
#pragma unroll
        for (int ni = 0; ni < 4; ++ni)
#pragma unroll
            for (int r = 0; r < 4; ++r) {
                int gr = m0 + wm * 64 + mi * 16 + lg * 4 + r;
                int col = nbase + wn * 64 + ni * 16 + lr;
                float v = acc[mi][ni][r] + b2cat[plane * 1024 + col];
                size_t idx = (size_t)gr * KD + col;
                if (plane == 0) {
                    hf hi = (hf)v;
                    Sh[idx] = hi; Sl[idx] = (hf)(v - (float)hi);
                } else if (plane == 1) So[idx] = (hf)v;
                else Ss[idx] = (hf)v;
            }
}

// ---------------------------------------------------------------- adj GEMM
// 128x128 tile, FUSED g-build in prefetch region, 2-pass W3h/W3l, 24KB LDS.
__global__ __launch_bounds__(256, 3) void k_adj_gemm(
    const hf* __restrict__ Sh, const hf* __restrict__ Sl,
    const float* __restrict__ e1, const float* __restrict__ e2,
    const hf* __restrict__ W3h, const hf* __restrict__ W3l,
    const float* __restrict__ b3, const float* __restrict__ aw,
    float* __restrict__ adjv) {
    __shared__ hf Ah[4096];
    __shared__ hf Bh[4096];
    __shared__ hf Bl[4096];
    const int tid = threadIdx.x;
    int lin = blockIdx.y * 8 + blockIdx.x;       // grid (8,128) = 1024, %8==0
    int xcd = lin & 7, slot = lin >> 3;          // slot 0..127
    const int nbase = (slot & 7) * 128;
    const int m0 = ((xcd << 4) + (slot >> 3)) * 128;
    const int lane = tid & 63, wid = tid >> 6;
    const int wm = wid >> 1, wn = wid & 1;
    const int lr = lane & 15, lg = lane >> 4;
    const int srow = tid >> 2, sseg = tid & 3;
    const int wo_ = srow * 32 + (sseg ^ ((srow >> 1) & 3)) * 8;
    const int rsl = (lg ^ ((lr >> 1) & 3)) * 8;
    const int ar0 = m0 + srow, ar1 = ar0 + 64;
    const int i0 = ar0 >> 8, j0 = ar0 & 255;
    const int i1 = ar1 >> 8, j1 = ar1 & 255;
    const int ko = sseg * 8;

    f4v acc[4][4];
    f4v zz; zz[0] = 0.f; zz[1] = 0.f; zz[2] = 0.f; zz[3] = 0.f;
#pragma unroll
    for (int a = 0; a < 4; ++a)
#pragma unroll
        for (int b = 0; b < 4; ++b) acc[a][b] = zz;

    h8v sh0, sl0, sh1, sl1;
    float4 ex00, ex01, ey00, ey01, ex10, ex11, ey10, ey11;
    h8v vb0, vb1, wb0, wb1;
    h8v gh0, gh1;
    auto LOAD = [&](int kk) {
        sh0 = *(const h8v*)(Sh + (size_t)ar0 * KD + ko + kk);
        sl0 = *(const h8v*)(Sl + (size_t)ar0 * KD + ko + kk);
        sh1 = *(const h8v*)(Sh + (size_t)ar1 * KD + ko + kk);
        sl1 = *(const h8v*)(Sl + (size_t)ar1 * KD + ko + kk);
        ex00 = *(const float4*)(e1 + (size_t)i0 * KD + ko + kk);
        ex01 = *(const float4*)(e1 + (size_t)i0 * KD + ko + kk + 4);
        ey00 = *(const float4*)(e2 + (size_t)j0 * KD + ko + kk);
        ey01 = *(const float4*)(e2 + (size_t)j0 * KD + ko + kk + 4);
        ex10 = *(const float4*)(e1 + (size_t)i1 * KD + ko + kk);
        ex11 = *(const float4*)(e1 + (size_t)i1 * KD + ko + kk + 4);
        ey10 = *(const float4*)(e2 + (size_t)j1 * KD + ko + kk);
        ey11 = *(const float4*)(e2 + (size_t)j1 * KD + ko + kk + 4);
        vb0 = *(const h8v*)(W3h + (size_t)(nbase + srow) * KD + ko + kk);
        vb1 = *(const h8v*)(W3h + (size_t)(nbase + 64 + srow) * KD + ko + kk);
        wb0 = *(const h8v*)(W3l + (size_t)(nbase + srow) * KD + ko + kk);
        wb1 = *(const h8v*)(W3l + (size_t)(nbase + 64 + srow) * KD + ko + kk);
    };
    auto BUILD = [&]() {
#pragma unroll
        for (int e = 0; e < 8; ++e) {
            float s = (float)sh0[e] + (float)sl0[e];
            float ee = f4at(ex00, ex01, e) + f4at(ey00, ey01, e);
            float gg = ee * s; gg = gg > 0.f ? gg : 0.f;
            gh0[e] = (hf)gg;
        }
#pragma unroll
        for (int e = 0; e < 8; ++e) {
            float s = (float)sh1[e] + (float)sl1[e];
            float ee = f4at(ex10, ex11, e) + f4at(ey10, ey11, e);
            float gg = ee * s; gg = gg > 0.f ? gg : 0.f;
            gh1[e] = (hf)gg;
        }
    };
    LOAD(0);
    BUILD();
    for (int t = 0; t < 32; ++t) {
        __syncthreads();
        *(h8v*)(Ah + wo_) = gh0; *(h8v*)(Ah + 2048 + wo_) = gh1;
        *(h8v*)(Bh + wo_) = vb0; *(h8v*)(Bh + 2048 + wo_) = vb1;
        *(h8v*)(Bl + wo_) = wb0; *(h8v*)(Bl + 2048 + wo_) = wb1;
        __syncthreads();
        if (t + 1 < 32) { LOAD((t + 1) * 32); BUILD(); }   // overlaps MFMA below
        h8v fa[4], fb[4];
#pragma unroll
        for (int x = 0; x < 4; ++x) {
            fa[x] = *(const h8v*)(Ah + (wm * 64 + x * 16 + lr) * 32 + rsl);
            fb[x] = *(const h8v*)(Bh + (wn * 64 + x * 16 + lr) * 32 + rsl);
        }
#pragma unroll
        for (int mi = 0; mi < 4; ++mi)
#pragma unroll
            for (int ni = 0; ni < 4; ++ni)
                acc[mi][ni] = __builtin_amdgcn_mfma_f32_16x16x32_f16(fa[mi], fb[ni], acc[mi][ni], 0, 0, 0);
#pragma unroll
        for (int x = 0; x < 4; ++x)
            fb[x] = *(const h8v*)(Bl + (wn * 64 + x * 16 + lr) * 32 + rsl);
#pragma unroll
        for (int mi = 0; mi < 4; ++mi)
#pragma unroll
            for (int ni = 0; ni < 4; ++ni)
                acc[mi][ni] = __builtin_amdgcn_mfma_f32_16x16x32_f16(fa[mi], fb[ni], acc[mi][ni], 0, 0, 0);
    }
    float b3v[4], awv[4];
#pragma unroll
    for (int ni = 0; ni < 4; ++ni) {
        int gc = nbase + wn * 64 + ni * 16 + lr;
        b3v[ni] = b3[gc]; awv[ni] = aw[gc];
    }
#pragma unroll
    for (int mi = 0; mi < 4; ++mi)
#pragma unroll
        for (int r = 0; r < 4; ++r) {
            float part = 0.f;
#pragma unroll
            for (int ni = 0; ni < 4; ++ni) {
                float w = acc[mi][ni][r] + b3v[ni];
                w = w > 0.f ? w : 0.f;
                part += w * awv[ni];
            }
            part += __shfl_xor(part, 1);
            part += __shfl_xor(part, 2);
            part += __shfl_xor(part, 4);
            part += __shfl_xor(part, 8);
            if (lr == 0) atomicAdd(adjv + m0 + wm * 64 + mi * 16 + lg * 4 + r, part);
        }
}

// ---------------------------------------------------------------- small routed GEMM (split-K 8)
struct SRoute { const hf* A; const hf* Bh; const hf* Bl; float* C; const float* bias; int m0; int M; };
struct SRoutes { SRoute r[5]; };

__global__ __launch_bounds__(256) void k_small(SRoutes RR) {
    const SRoute rt = RR.r[blockIdx.y];
    __shared__ hf Ah[4096];
    __shared__ hf Bh[4096];
    __shared__ hf Bl[4096];
    const int tid = threadIdx.x;
    const int n0 = blockIdx.x * 128;
    const int kbeg = blockIdx.z * 128;
    const int lane = tid & 63, wid = tid >> 6;
    const int wm = wid >> 1, wn = wid & 1;
    const int lr = lane & 15, lg = lane >> 4;
    const int srow = tid >> 2, sseg = tid & 3;
    const int wo_ = srow * 32 + (sseg ^ ((srow >> 1) & 3)) * 8;
    const int rsl = (lg ^ ((lr >> 1) & 3)) * 8;
    int ar0 = rt.m0 + srow;      if (ar0 >= rt.M) ar0 = rt.M - 1;
    int ar1 = rt.m0 + 64 + srow; if (ar1 >= rt.M) ar1 = rt.M - 1;
    const bool hasL = rt.Bl != nullptr;
    const int ko = kbeg + sseg * 8;

    f4v acc[4][4];
    f4v zz; zz[0] = 0.f; zz[1] = 0.f; zz[2] = 0.f; zz[3] = 0.f;
#pragma unroll
    for (int a = 0; a < 4; ++a)
#pragma unroll
        for (int b = 0; b < 4; ++b) acc[a][b] = zz;

    h8v va0, va1, vb0, vb1, wb0, wb1;
    auto LOAD = [&](int kk) {
        va0 = *(const h8v*)(rt.A + (size_t)ar0 * KD + ko + kk);
        va1 = *(const h8v*)(rt.A + (size_t)ar1 * KD + ko + kk);
        vb0 = *(const h8v*)(rt.Bh + (size_t)(n0 + srow) * KD + ko + kk);
        vb1 = *(const h8v*)(rt.Bh + (size_t)(n0 + 64 + srow) * KD + ko + kk);
        if (hasL) {
            wb0 = *(const h8v*)(rt.Bl + (size_t)(n0 + srow) * KD + ko + kk);
            wb1 = *(const h8v*)(rt.Bl + (size_t)(n0 + 64 + srow) * KD + ko + kk);
        }
    };
    LOAD(0);
    for (int t = 0; t < 4; ++t) {
        __syncthreads();
        *(h8v*)(Ah + wo_) = va0; *(h8v*)(Ah + 2048 + wo_) = va1;
        *(h8v*)(Bh + wo_) = vb0; *(h8v*)(Bh + 2048 + wo_) = vb1;
        if (hasL) { *(h8v*)(Bl + wo_) = wb0; *(h8v*)(Bl + 2048 + wo_) = wb1; }
        __syncthreads();
        if (t + 1 < 4) LOAD((t + 1) * 32);
        h8v fa[4], fb[4];
#pragma unroll
        for (int x = 0; x < 4; ++x) {
            fa[x] = *(const h8v*)(Ah + (wm * 64 + x * 16 + lr) * 32 + rsl);
            fb[x] = *(const h8v*)(Bh + (wn * 64 + x * 16 + lr) * 32 + rsl);
        }
#pragma unroll
        for (int mi = 0; mi < 4; ++mi)
#pragma unroll
            for (int ni = 0; ni < 4; ++ni)
                acc[mi][ni] = __builtin_amdgcn_mfma_f32_16x16x32_f16(fa[mi], fb[ni], acc[mi][ni], 0, 0, 0);
        if (hasL) {
#pragma unroll
            for (int x = 0; x < 4; ++x)
                fb[x] = *(const h8v*)(Bl + (wn * 64 + x * 16 + lr) * 32 + rsl);
#pragma unroll
            for (int mi = 0; mi < 4; ++mi)
#pragma unroll
                for (int ni = 0; ni < 4; ++ni)
                    acc[mi][ni] = __builtin_amdgcn_mfma_f32_16x16x32_f16(fa[mi], fb[ni], acc[mi][ni], 0, 0, 0);
        }
    }
#pragma unroll
    for (int mi = 0; mi < 4; ++mi)
#pragma unroll
        for (int ni = 0; ni < 4; ++ni)
#pragma unroll
            for (int r = 0; r < 4; ++r) {
                int gr = rt.m0 + wm * 64 + mi * 16 + lg * 4 + r;
                int gc = n0 + wn * 64 + ni * 16 + lr;
                if (gr < rt.M) {
                    float v = acc[mi][ni][r];
                    if (rt.bias && blockIdx.z == 0) v += rt.bias[gc];
                    atomicAdd(rt.C + (size_t)gr * KD + gc, v);
                }
            }
}

// ---------------------------------------------------------------- softmax (rows + cols in one launch)
__global__ void k_softmax_both(const float* __restrict__ adj, float* __restrict__ p,
                               float* __restrict__ q) {
    int b = blockIdx.x;
    if (b < NS) {
        __shared__ float red[256];
        int i = b, j = threadIdx.x;
        float x = adj[i * 256 + j];
        red[j] = x; __syncthreads();
        for (int s = 128; s > 0; s >>= 1) { if (j < s) red[j] = fmaxf(red[j], red[j + s]); __syncthreads(); }
        float mx = red[0]; __syncthreads();
        float e = __expf(x - mx);
        red[j] = e; __syncthreads();
        for (int s = 128; s > 0; s >>= 1) { if (j < s) red[j] += red[j + s]; __syncthreads(); }
        p[i * 256 + j] = e / red[0];
    } else {
        int j = (b - NS) * 4 + (threadIdx.x >> 6);   // 4 cols per block, 1 wave each
        int i = threadIdx.x & 63;
        float x = adj[i * 256 + j];
        float mx = x;
#pragma unroll
        for (int off = 32; off > 0; off >>= 1) mx = fmaxf(mx, __shfl_xor(mx, off));
        float e = __expf(x - mx);
        float s = e;
#pragma unroll
        for (int off = 32; off > 0; off >>= 1) s += __shfl_xor(s, off);
        q[i * 256 + j] = e / s;
    }
}

__global__ void k_build_Gh(const hf* __restrict__ S, const float* __restrict__ aF,
                           const float* __restrict__ p, hf* __restrict__ Gh) {
    __shared__ float pl[256];
    int i = blockIdx.x;
    int k = blockIdx.y * 256 + threadIdx.x;
    pl[threadIdx.x] = p[i * 256 + threadIdx.x];
    __syncthreads();
    const hf* sp = S + (size_t)(i * 256) * KD + k;
    float acc = 0.f;
#pragma unroll 4
    for (int j = 0; j < 256; ++j) {
        float a = aF[(size_t)j * KD + k];
        float s = (float)sp[(size_t)j * KD];
        float g = a * s; g = g > 0.f ? g : 0.f;
        acc += pl[j] * g;
    }
    Gh[(size_t)i * KD + k] = (hf)acc;
}

__global__ void k_build_Go(const hf* __restrict__ S, const float* __restrict__ aF,
                           const float* __restrict__ q, hf* __restrict__ Go) {
    __shared__ float ql[64];
    int j = blockIdx.x;
    int k = blockIdx.y * 256 + threadIdx.x;
    if (threadIdx.x < 64) ql[threadIdx.x] = q[threadIdx.x * 256 + j];
    __syncthreads();
    const hf* sp = S + (size_t)j * KD + k;
    float acc = 0.f;
#pragma unroll 4
    for (int i = 0; i < 64; ++i) {
        float a = aF[(size_t)i * KD + k];
        float s = (float)sp[(size_t)(i * 256) * KD];
        float g = a * s; g = g > 0.f ? g : 0.f;
        acc += ql[i] * g;
    }
    Go[(size_t)j * KD + k] = (hf)acc;
}

__global__ void k_ln_update(float* __restrict__ x, const float* __restrict__ msg,
                            const float* __restrict__ b3, const float* __restrict__ gamma,
                            const float* __restrict__ beta, hf* __restrict__ x16) {
    __shared__ float red[256];
    int r = blockIdx.x, t = threadIdx.x;
    float v[4];
    float s = 0.f;
#pragma unroll
    for (int e = 0; e < 4; ++e) {
        int idx = t + e * 256;
        float mm = msg[(size_t)r * KD + idx] + b3[idx];
        mm = mm > 0.f ? mm : 0.f;
        v[e] = x[(size_t)r * KD + idx] + mm;
        s += v[e];
    }
    red[t] = s; __syncthreads();
    for (int st = 128; st > 0; st >>= 1) { if (t < st) red[t] += red[t + st]; __syncthreads(); }
    float mean = red[0] * (1.f / 1024.f);
    __syncthreads();
    float s2 = 0.f;
#pragma unroll
    for (int e = 0; e < 4; ++e) { float d = v[e] - mean; s2 += d * d; }
    red[t] = s2; __syncthreads();
    for (int st = 128; st > 0; st >>= 1) { if (t < st) red[t] += red[t + st]; __syncthreads(); }
    float var = red[0] * (1.f / 1024.f);
    float rstd = rsqrtf(var + 1e-5f);
#pragma unroll
    for (int e = 0; e < 4; ++e) {
        int idx = t + e * 256;
        float y = (v[e] - mean) * rstd * gamma[idx] + beta[idx];
        x[(size_t)r * KD + idx] = y;
        x16[(size_t)r * KD + idx] = (hf)y;
    }
}

// ---------------------------------------------------------------- launch
extern "C" void kernel_launch(void* const* d_in, const int* in_sizes, int n_in,
                              void* d_out, int out_size, void* d_ws, size_t ws_size,
                              hipStream_t stream) {
    const float* h_in    = (const float*)d_in[0];
    const float* o_in    = (const float*)d_in[1];
    const float* spatial = (const float*)d_in[2];
    const float* att_w1  = (const float*)d_in[3];
    const float* att_b1  = (const float*)d_in[4];
    const float* att_w2  = (const float*)d_in[5];
    const float* att_b2  = (const float*)d_in[6];
    const float* att_w3  = (const float*)d_in[7];
    const float* att_b3  = (const float*)d_in[8];
    const float* s2o_w1  = (const float*)d_in[9];
    const float* s2o_b1  = (const float*)d_in[10];
    const float* s2o_w2  = (const float*)d_in[11];
    const float* s2o_b2  = (const float*)d_in[12];
    const float* s2o_w3  = (const float*)d_in[13];
    const float* s2o_b3  = (const float*)d_in[14];
    const float* o2s_w1  = (const float*)d_in[15];
    const float* o2s_b1  = (const float*)d_in[16];
    const float* o2s_w2  = (const float*)d_in[17];
    const float* o2s_b2  = (const float*)d_in[18];
    const float* o2s_w3  = (const float*)d_in[19];
    const float* o2s_b3  = (const float*)d_in[20];
    const float* adj_w   = (const float*)d_in[21];
    const float* ns_g    = (const float*)d_in[23];
    const float* ns_b    = (const float*)d_in[24];
    const float* no_g    = (const float*)d_in[25];
    const float* no_b    = (const float*)d_in[26];
    // adj_b (d_in[22]) dropped: softmax is shift-invariant.

    char* ws = (char*)d_ws;
    size_t off = 0;
    auto alloc = [&](size_t bytes) -> char* {
        char* pp = ws + off;
        off += (bytes + 255) & ~(size_t)255;
        return pp;
    };
    const size_t PLANE = (size_t)MP * KD * sizeof(hf);     // 32MB
    const size_t WMAT  = (size_t)1024 * 1024 * sizeof(hf); // 2MB
    hf* S_att_h = (hf*)alloc(PLANE);
    hf* S_att_l = (hf*)alloc(PLANE);
    hf* S_o2s   = (hf*)alloc(PLANE);
    hf* S_s2o   = (hf*)alloc(PLANE);
    hf* sp16    = (hf*)alloc(PLANE);
    hf* W2att_h = (hf*)alloc(WMAT); hf* W2att_l = (hf*)alloc(WMAT);
    hf* W2o2s   = (hf*)alloc(WMAT);
    hf* W2s2o   = (hf*)alloc(WMAT);
    hf* W1ah_h  = (hf*)alloc(WMAT); hf* W1ah_l  = (hf*)alloc(WMAT);
    hf* W1ao_h  = (hf*)alloc(WMAT); hf* W1ao_l  = (hf*)alloc(WMAT);
    hf* W1o2s   = (hf*)alloc(WMAT);
    hf* W1s2o   = (hf*)alloc(WMAT);
    hf* W3a_h   = (hf*)alloc(WMAT); hf* W3a_l   = (hf*)alloc(WMAT);
    hf* W3o     = (hf*)alloc(WMAT);
    hf* W3s     = (hf*)alloc(WMAT);
    float* b2cat = (float*)alloc(3072 * 4);
    float* b3a   = (float*)alloc(1024 * 4);
    float* b3o   = (float*)alloc(1024 * 4);
    float* b3s   = (float*)alloc(1024 * 4);
    // contiguous zero-region (one memset per iteration)
    float* fc1h = (float*)alloc((size_t)NS * KD * 4);
    float* fc1o = (float*)alloc((size_t)NO * KD * 4);
    float* aO2S = (float*)alloc((size_t)NO * KD * 4);
    float* aS2O = (float*)alloc((size_t)NS * KD * 4);
    float* msgh = (float*)alloc((size_t)NS * KD * 4);
    float* msgo = (float*)alloc((size_t)NO * KD * 4);
    float* adjv = (float*)alloc((size_t)MP * 4);
    char* zend_ = (char*)(adjv + MP);
    size_t zlen = (size_t)(zend_ - (char*)fc1h);
    float* pbuf = (float*)alloc((size_t)MP * 4);
    float* qbuf = (float*)alloc((size_t)MP * 4);
    hf* h16 = (hf*)alloc((size_t)NS * KD * sizeof(hf));
    hf* o16 = (hf*)alloc((size_t)NO * KD * sizeof(hf));
    hf* Gh  = (hf*)alloc((size_t)NS * KD * sizeof(hf));
    hf* Go  = (hf*)alloc((size_t)NO * KD * sizeof(hf));

    float* hbuf = (float*)d_out;             // [64,1024]
    float* obuf = (float*)d_out + NS * KD;   // [256,1024]

    // ---- prep (iteration-invariant) ----
    k_pack16<<<dim3(MP * KD / 8 / 256), 256, 0, stream>>>(spatial, sp16, MP * KD / 8);
    {
        RoRs R;
        R.r[0] = { att_w2, W2att_h, W2att_l, 1024, 0 };
        R.r[1] = { o2s_w2, W2o2s, nullptr, 1024, 0 };
        R.r[2] = { s2o_w2, W2s2o, nullptr, 1024, 0 };
        R.r[3] = { att_w1, W1ah_h, W1ah_l, 2048, 0 };
        R.r[4] = { att_w1, W1ao_h, W1ao_l, 2048, 1024 };
        R.r[5] = { o2s_w1, W1o2s, nullptr, 1024, 0 };
        R.r[6] = { s2o_w1, W1s2o, nullptr, 1024, 0 };
        k_reorder16b<<<dim3(16, 16, 7), 256, 0, stream>>>(R);
    }
    {
        TrRs T;
        T.r[0] = { att_w3, W3a_h, W3a_l };
        T.r[1] = { o2s_w3, W3o, nullptr };
        T.r[2] = { s2o_w3, W3s, nullptr };
        k_transpose16b<<<dim3(16, 16, 3), 256, 0, stream>>>(T);
    }
    k_prep_bc<<<dim3(4), 256, 0, stream>>>(att_b2, o2s_b2, s2o_b2, att_b3, o2s_b3, s2o_b3,
                                           b2cat, b3a, b3o, b3s);
    k_init_ho<<<dim3(1280), 256, 0, stream>>>(h_in, o_in, (float*)d_out, h16, o16);
    k_prep_gemm<<<dim3(24, 128), 256, 0, stream>>>(sp16, W2att_h, W2att_l, W2o2s, W2s2o,
                                                   b2cat, S_att_h, S_att_l, S_o2s, S_s2o);

    for (int it = 0; it < 2; ++it) {
        hipMemsetAsync(fc1h, 0, zlen, stream);
        // fc1h = h@W1ah(+lo)+b1 ; fc1o = o@W1ao(+lo) ; aO2S = o@W1o2s+b1
        {
            SRoutes R;
            R.r[0] = { h16, W1ah_h, W1ah_l, fc1h, att_b1, 0,   NS };
            R.r[1] = { o16, W1ao_h, W1ao_l, fc1o, nullptr, 0,   NO };
            R.r[2] = { o16, W1ao_h, W1ao_l, fc1o, nullptr, 128, NO };
            R.r[3] = { o16, W1o2s,  nullptr, aO2S, o2s_b1, 0,   NO };
            R.r[4] = { o16, W1o2s,  nullptr, aO2S, o2s_b1, 128, NO };
            k_small<<<dim3(8, 5, 8), 256, 0, stream>>>(R);
        }
        k_adj_gemm<<<dim3(8, 128), 256, 0, stream>>>(S_att_h, S_att_l, fc1h, fc1o,
                                                     W3a_h, W3a_l, b3a, adj_w, adjv);
        k_softmax_both<<<dim3(NS + NO / 4), 256, 0, stream>>>(adjv, pbuf, qbuf);
        // h update
        k_build_Gh<<<dim3(NS, 4), 256, 0, stream>>>(S_o2s, aO2S, pbuf, Gh);
        {
            SRoutes R;
            R.r[0] = { Gh, W3o, nullptr, msgh, nullptr, 0, NS };
            k_small<<<dim3(8, 1, 8), 256, 0, stream>>>(R);
        }
        k_ln_update<<<dim3(NS), 256, 0, stream>>>(hbuf, msgh, b3o, ns_g, ns_b, h16);
        // o update (uses updated h)
        {
            SRoutes R;
            R.r[0] = { h16, W1s2o, nullptr, aS2O, s2o_b1, 0, NS };
            k_small<<<dim3(8, 1, 8), 256, 0, stream>>>(R);
        }
        k_build_Go<<<dim3(NO, 4), 256, 0, stream>>>(S_s2o, aS2O, qbuf, Go);
        {
            SRoutes R;
            R.r[0] = { Go, W3s, nullptr, msgo, nullptr, 0,   NO };
            R.r[1] = { Go, W3s, nullptr, msgo, nullptr, 128, NO };
            k_small<<<dim3(8, 2, 8), 256, 0, stream>>>(R);
        }
        k_ln_update<<<dim3(NO), 256, 0, stream>>>(obuf, msgo, b3s, no_g, no_b, o16);
    }
    (void)in_sizes; (void)n_in; (void)out_size; (void)ws_size;
}

// Round 16
// 614.699 us; speedup vs baseline: 1.2023x; 1.2023x over previous
//
#include <hip/hip_runtime.h>
#include <cstdint>
#include <cstddef>

typedef _Float16 hf;
typedef _Float16 h8v __attribute__((ext_vector_type(8)));
typedef float f4v __attribute__((ext_vector_type(4)));

#define NS 64
#define NO 256
#define MP 16384
#define KD 1024

__device__ __forceinline__ h8v cvt8(float4 a, float4 b) {
    h8v r;
    r[0] = (hf)a.x; r[1] = (hf)a.y; r[2] = (hf)a.z; r[3] = (hf)a.w;
    r[4] = (hf)b.x; r[5] = (hf)b.y; r[6] = (hf)b.z; r[7] = (hf)b.w;
    return r;
}
__device__ __forceinline__ float f4at(const float4& a, const float4& b, int e) {
    const float* p = e < 4 ? (const float*)&a : (const float*)&b;
    return p[e & 3];
}
// HBM -> LDS DMA, 16B per lane, linear dest (wave-uniform base + lane*16)
__device__ __forceinline__ void gl16(const hf* g, hf* l) {
    __builtin_amdgcn_global_load_lds(
        (const __attribute__((address_space(1))) void*)g,
        (__attribute__((address_space(3))) void*)l, 16, 0, 0);
}

// ---------------------------------------------------------------- fp32 -> fp16 pack
__global__ void k_pack16(const float* __restrict__ src, hf* __restrict__ dst, int n8) {
    int g = blockIdx.x * 256 + threadIdx.x;
    if (g >= n8) return;
    const float4* s4 = (const float4*)src;
    float4 a = s4[2 * g], b = s4[2 * g + 1];
    *(h8v*)(dst + (size_t)g * 8) = cvt8(a, b);
}

// ---------------------------------------------------------------- batched weight prep
struct RoR { const float* src; hf* dhi; hf* dlo; int Asrc; int aOff; };
struct RoRs { RoR r[7]; };
__global__ void k_reorder16b(RoRs RR) {
    const RoR rt = RR.r[blockIdx.z];
    __shared__ float tile[64][65];
    int c = blockIdx.x, a0 = blockIdx.y * 64;
    int t = threadIdx.x, lx = t & 63, ly = t >> 6;
#pragma unroll
    for (int p = 0; p < 16; ++p) {
        int ar = ly + p * 4;
        tile[ar][lx] = rt.src[(size_t)(c * rt.Asrc + rt.aOff + a0 + ar) * 64 + lx];
    }
    __syncthreads();
#pragma unroll
    for (int p = 0; p < 16; ++p) {
        int d = ly + p * 4;
        float v = tile[lx][d];
        hf h = (hf)v;
        size_t idx = (size_t)(c * 64 + d) * 1024 + a0 + lx;
        rt.dhi[idx] = h;
        if (rt.dlo) rt.dlo[idx] = (hf)(v - (float)h);
    }
}

struct TrR { const float* src; hf* dhi; hf* dlo; };
struct TrRs { TrR r[3]; };
__global__ void k_transpose16b(TrRs RR) {
    const TrR rt = RR.r[blockIdx.z];
    __shared__ float tile[64][65];
    int r0 = blockIdx.x * 64, s0 = blockIdx.y * 64;
    int t = threadIdx.x, lx = t & 63, ly = t >> 6;
#pragma unroll
    for (int p = 0; p < 16; ++p) {
        int srow = ly + p * 4;
        tile[srow][lx] = rt.src[(size_t)(s0 + srow) * 1024 + r0 + lx];
    }
    __syncthreads();
#pragma unroll
    for (int p = 0; p < 16; ++p) {
        int rr = ly + p * 4;
        float v = tile[lx][rr];
        hf h = (hf)v;
        size_t idx = (size_t)(r0 + rr) * 1024 + s0 + lx;
        rt.dhi[idx] = h;
        if (rt.dlo) rt.dlo[idx] = (hf)(v - (float)h);
    }
}

__global__ void k_prep_bc(const float* __restrict__ ab2, const float* __restrict__ ob2,
                          const float* __restrict__ sb2, const float* __restrict__ ab3,
                          const float* __restrict__ ob3, const float* __restrict__ sb3,
                          float* __restrict__ b2cat, float* __restrict__ b3a,
                          float* __restrict__ b3o, float* __restrict__ b3s) {
    int g = blockIdx.x * 256 + threadIdx.x;
    if (g >= 1024) return;
    b2cat[g] = ab2[g]; b2cat[1024 + g] = ob2[g]; b2cat[2048 + g] = sb2[g];
    float sa = 0.f, so = 0.f, ss = 0.f;
    for (int c = 0; c < 16; ++c) {
        sa += ab3[c * 1024 + g];
        so += ob3[c * 1024 + g];
        ss += sb3[c * 1024 + g];
    }
    b3a[g] = sa; b3o[g] = so; b3s[g] = ss;
}

__global__ void k_init_ho(const float* __restrict__ h, const float* __restrict__ o,
                          float* __restrict__ outbuf, hf* __restrict__ h16, hf* __restrict__ o16) {
    int g = blockIdx.x * 256 + threadIdx.x;
    if (g < NS * KD) { float v = h[g]; outbuf[g] = v; h16[g] = (hf)v; }
    int g2 = g - NS * KD;
    if (g2 >= 0 && g2 < NO * KD) { float v = o[g2]; outbuf[NS * KD + g2] = v; o16[g2] = (hf)v; }
}

// ---------------------------------------------------------------- prep GEMM (one-time, r15 form)
// 128x128 tile, acc 4x4 (64 AGPR), gload_lds DMA staging, 24KB LDS -> high occupancy.
__global__ __launch_bounds__(256, 4) void k_prep_gemm(
    const hf* __restrict__ sp16,
    const hf* __restrict__ Wah, const hf* __restrict__ Wal,
    const hf* __restrict__ Wo2, const hf* __restrict__ Ws2,
    const float* __restrict__ b2cat,
    hf* __restrict__ Sh, hf* __restrict__ Sl,
    hf* __restrict__ So, hf* __restrict__ Ss) {
    __shared__ hf Ah[4096];
    __shared__ hf Bh[4096];
    __shared__ hf Bl[4096];
    const int tid = threadIdx.x;
    int lin = blockIdx.y * 24 + blockIdx.x;      // grid (24,128) = 3072, %8==0
    int xcd = lin & 7, slot = lin >> 3;          // slot 0..383
    int xn = slot % 24;
    const int m0 = ((xcd << 4) + slot / 24) * 128;
    const int plane = xn >> 3;                   // 0 att, 1 o2s, 2 s2o
    const int nbase = (xn & 7) * 128;
    const hf* Bb = plane == 0 ? Wah : (plane == 1 ? Wo2 : Ws2);
    const bool hasL = (plane == 0);
    const int lane = tid & 63, wid = tid >> 6;
    const int wm = wid >> 1, wn = wid & 1;
    const int lr = lane & 15, lg = lane >> 4;
    const int rsl = (lg ^ ((lr >> 1) & 3)) * 8;

    const int crow = lane >> 2;
    const int gseg = ((lane & 3) ^ ((lane >> 3) & 3)) * 8;
    hf* ldsA0 = Ah + wid * 512;         hf* ldsA1 = Ah + 2048 + wid * 512;
    hf* ldsB0 = Bh + wid * 512;         hf* ldsB1 = Bh + 2048 + wid * 512;
    hf* ldsL0 = Bl + wid * 512;         hf* ldsL1 = Bl + 2048 + wid * 512;
    const hf* gA0 = sp16 + (size_t)(m0 +      wid * 16 + crow) * KD + gseg;
    const hf* gA1 = sp16 + (size_t)(m0 + 64 + wid * 16 + crow) * KD + gseg;
    const hf* gB0 = Bb  + (size_t)(nbase +      wid * 16 + crow) * KD + gseg;
    const hf* gB1 = Bb  + (size_t)(nbase + 64 + wid * 16 + crow) * KD + gseg;
    const hf* gL0 = Wal + (size_t)(nbase +      wid * 16 + crow) * KD + gseg;
    const hf* gL1 = Wal + (size_t)(nbase + 64 + wid * 16 + crow) * KD + gseg;

    f4v acc[4][4];
    f4v zz; zz[0] = 0.f; zz[1] = 0.f; zz[2] = 0.f; zz[3] = 0.f;
#pragma unroll
    for (int a = 0; a < 4; ++a)
#pragma unroll
        for (int b = 0; b < 4; ++b) acc[a][b] = zz;

    for (int t = 0; t < 32; ++t) {
        const int kk = t * 32;
        __syncthreads();
        gl16(gA0 + kk, ldsA0); gl16(gA1 + kk, ldsA1);
        gl16(gB0 + kk, ldsB0); gl16(gB1 + kk, ldsB1);
        if (hasL) { gl16(gL0 + kk, ldsL0); gl16(gL1 + kk, ldsL1); }
        __syncthreads();
        h8v fa[4], fb[4];
#pragma unroll
        for (int x = 0; x < 4; ++x) {
            fa[x] = *(const h8v*)(Ah + (wm * 64 + x * 16 + lr) * 32 + rsl);
            fb[x] = *(const h8v*)(Bh + (wn * 64 + x * 16 + lr) * 32 + rsl);
        }
#pragma unroll
        for (int mi = 0; mi < 4; ++mi)
#pragma unroll
            for (int ni = 0; ni < 4; ++ni)
                acc[mi][ni] = __builtin_amdgcn_mfma_f32_16x16x32_f16(fa[mi], fb[ni], acc[mi][ni], 0, 0, 0);
        if (hasL) {
#pragma unroll
            for (int x = 0; x < 4; ++x)
                fb[x] = *(const h8v*)(Bl + (wn * 64 + x * 16 + lr) * 32 + rsl);
#pragma unroll
            for (int mi = 0; mi < 4; ++mi)
#pragma unroll
                for (int ni = 0; ni < 4; ++ni)
                    acc[mi][ni] = __builtin_amdgcn_mfma_f32_16x16x32_f16(fa[mi], fb[ni], acc[mi][ni], 0, 0, 0);
        }
    }
#pragma unroll
    for (int mi = 0; mi < 4; ++mi)
#pragma unroll
        for (int ni = 0; ni < 4; ++ni)
#pragma unroll
            for (int r = 0; r < 4; ++r) {
                int gr = m0 + wm * 64 + mi * 16 + lg * 4 + r;
                int col = nbase + wn * 64 + ni * 16 + lr;
                float v = acc[mi][ni][r] + b2cat[plane * 1024 + col];
                size_t idx = (size_t)gr * KD + col;
                if (plane == 0) {
                    hf hi = (hf)v;
                    Sh[idx] = hi; Sl[idx] = (hf)(v - (float)hi);
                } else if (plane == 1) So[idx] = (hf)v;
                else Ss[idx] = (hf)v;
            }
}

// ---------------------------------------------------------------- adj GEMM (r14 form)
// N=256/block, FUSED g-build in prefetch region (overlaps MFMA), 2-pass W3h/W3l.
__global__ __launch_bounds__(256, 2) void k_adj_gemm(
    const hf* __restrict__ Sh, const hf* __restrict__ Sl,
    const float* __restrict__ e1, const float* __restrict__ e2,
    const hf* __restrict__ W3h, const hf* __restrict__ W3l,
    const float* __restrict__ b3, const float* __restrict__ aw,
    float* __restrict__ adjv) {
    __shared__ hf Ah[4096];
    __shared__ hf Bh[8192];
    __shared__ hf Bl[8192];
    const int tid = threadIdx.x;
    int lin = blockIdx.y * 4 + blockIdx.x;       // grid (4,128) = 512 blocks, %8==0
    int xcd = lin & 7, slot = lin >> 3;
    const int nbase = (slot & 3) * 256;
    const int m0 = ((xcd << 4) + (slot >> 2)) * 128;
    const int lane = tid & 63, wid = tid >> 6;
    const int wm = wid >> 1, wn = wid & 1;
    const int lr = lane & 15, lg = lane >> 4;
    const int srow = tid >> 2, sseg = tid & 3;
    const int wo_ = srow * 32 + (sseg ^ ((srow >> 1) & 3)) * 8;
    const int rsl = (lg ^ ((lr >> 1) & 3)) * 8;
    const int ar0 = m0 + srow, ar1 = ar0 + 64;
    const int i0 = ar0 >> 8, j0 = ar0 & 255;
    const int i1 = ar1 >> 8, j1 = ar1 & 255;
    const int ko = sseg * 8;

    f4v acc[2][4][4];
    f4v zz; zz[0] = 0.f; zz[1] = 0.f; zz[2] = 0.f; zz[3] = 0.f;
#pragma unroll
    for (int u = 0; u < 2; ++u)
#pragma unroll
        for (int a = 0; a < 4; ++a)
#pragma unroll
            for (int b = 0; b < 4; ++b) acc[u][a][b] = zz;

    h8v sh0, sl0, sh1, sl1;
    float4 ex00, ex01, ey00, ey01, ex10, ex11, ey10, ey11;
    h8v vb00, vb01, vb10, vb11, wb00, wb01, wb10, wb11;
    h8v gh0, gh1;
    auto LOAD = [&](int kk) {
        sh0 = *(const h8v*)(Sh + (size_t)ar0 * KD + ko + kk);
        sl0 = *(const h8v*)(Sl + (size_t)ar0 * KD + ko + kk);
        sh1 = *(const h8v*)(Sh + (size_t)ar1 * KD + ko + kk);
        sl1 = *(const h8v*)(Sl + (size_t)ar1 * KD + ko + kk);
        ex00 = *(const float4*)(e1 + (size_t)i0 * KD + ko + kk);
        ex01 = *(const float4*)(e1 + (size_t)i0 * KD + ko + kk + 4);
        ey00 = *(const float4*)(e2 + (size_t)j0 * KD + ko + kk);
        ey01 = *(const float4*)(e2 + (size_t)j0 * KD + ko + kk + 4);
        ex10 = *(const float4*)(e1 + (size_t)i1 * KD + ko + kk);
        ex11 = *(const float4*)(e1 + (size_t)i1 * KD + ko + kk + 4);
        ey10 = *(const float4*)(e2 + (size_t)j1 * KD + ko + kk);
        ey11 = *(const float4*)(e2 + (size_t)j1 * KD + ko + kk + 4);
        vb00 = *(const h8v*)(W3h + (size_t)(nbase + srow) * KD + ko + kk);
        vb01 = *(const h8v*)(W3h + (size_t)(nbase + 64 + srow) * KD + ko + kk);
        vb10 = *(const h8v*)(W3h + (size_t)(nbase + 128 + srow) * KD + ko + kk);
        vb11 = *(const h8v*)(W3h + (size_t)(nbase + 192 + srow) * KD + ko + kk);
        wb00 = *(const h8v*)(W3l + (size_t)(nbase + srow) * KD + ko + kk);
        wb01 = *(const h8v*)(W3l + (size_t)(nbase + 64 + srow) * KD + ko + kk);
        wb10 = *(const h8v*)(W3l + (size_t)(nbase + 128 + srow) * KD + ko + kk);
        wb11 = *(const h8v*)(W3l + (size_t)(nbase + 192 + srow) * KD + ko + kk);
    };
    auto BUILD = [&]() {
#pragma unroll
        for (int e = 0; e < 8; ++e) {
            float s = (float)sh0[e] + (float)sl0[e];
            float ee = f4at(ex00, ex01, e) + f4at(ey00, ey01, e);
            float gg = ee * s; gg = gg > 0.f ? gg : 0.f;
            gh0[e] = (hf)gg;
        }
#pragma unroll
        for (int e = 0; e < 8; ++e) {
            float s = (float)sh1[e] + (float)sl1[e];
            float ee = f4at(ex10, ex11, e) + f4at(ey10, ey11, e);
            float gg = ee * s; gg = gg > 0.f ? gg : 0.f;
            gh1[e] = (hf)gg;
        }
    };
    LOAD(0);
    BUILD();
    for (int t = 0; t < 32; ++t) {
        __syncthreads();
        *(h8v*)(Ah + wo_) = gh0; *(h8v*)(Ah + 2048 + wo_) = gh1;
        *(h8v*)(Bh + wo_) = vb00; *(h8v*)(Bh + 2048 + wo_) = vb01;
        *(h8v*)(Bh + 4096 + wo_) = vb10; *(h8v*)(Bh + 6144 + wo_) = vb11;
        *(h8v*)(Bl + wo_) = wb00; *(h8v*)(Bl + 2048 + wo_) = wb01;
        *(h8v*)(Bl + 4096 + wo_) = wb10; *(h8v*)(Bl + 6144 + wo_) = wb11;
        __syncthreads();
        if (t + 1 < 32) { LOAD((t + 1) * 32); BUILD(); }   // overlaps MFMA below
        h8v fa[4], fb[4];
#pragma unroll
        for (int x = 0; x < 4; ++x)
            fa[x] = *(const h8v*)(Ah + (wm * 64 + x * 16 + lr) * 32 + rsl);
#pragma unroll
        for (int u = 0; u < 2; ++u) {
#pragma unroll
            for (int x = 0; x < 4; ++x)
                fb[x] = *(const h8v*)(Bh + u * 4096 + (wn * 64 + x * 16 + lr) * 32 + rsl);
#pragma unroll
            for (int mi = 0; mi < 4; ++mi)
#pragma unroll
                for (int ni = 0; ni < 4; ++ni)
                    acc[u][mi][ni] = __builtin_amdgcn_mfma_f32_16x16x32_f16(fa[mi], fb[ni], acc[u][mi][ni], 0, 0, 0);
#pragma unroll
            for (int x = 0; x < 4; ++x)
                fb[x] = *(const h8v*)(Bl + u * 4096 + (wn * 64 + x * 16 + lr) * 32 + rsl);
#pragma unroll
            for (int mi = 0; mi < 4; ++mi)
#pragma unroll
                for (int ni = 0; ni < 4; ++ni)
                    acc[u][mi][ni] = __builtin_amdgcn_mfma_f32_16x16x32_f16(fa[mi], fb[ni], acc[u][mi][ni], 0, 0, 0);
        }
    }
    float b3v[2][4], awv[2][4];
#pragma unroll
    for (int u = 0; u < 2; ++u)
#pragma unroll
        for (int ni = 0; ni < 4; ++ni) {
            int gc = nbase + u * 128 + wn * 64 + ni * 16 + lr;
            b3v[u][ni] = b3[gc]; awv[u][ni] = aw[gc];
        }
#pragma unroll
    for (int mi = 0; mi < 4; ++mi)
#pragma unroll
        for (int r = 0; r < 4; ++r) {
            float part = 0.f;
#pragma unroll
            for (int u = 0; u < 2; ++u)
#pragma unroll
                for (int ni = 0; ni < 4; ++ni) {
                    float w = acc[u][mi][ni][r] + b3v[u][ni];
                    w = w > 0.f ? w : 0.f;
                    part += w * awv[u][ni];
                }
            part += __shfl_xor(part, 1);
            part += __shfl_xor(part, 2);
            part += __shfl_xor(part, 4);
            part += __shfl_xor(part, 8);
            if (lr == 0) atomicAdd(adjv + m0 + wm * 64 + mi * 16 + lg * 4 + r, part);
        }
}

// ---------------------------------------------------------------- small routed GEMM (split-K 8)
struct SRoute { const hf* A; const hf* Bh; const hf* Bl; float* C; const float* bias; int m0; int M; };
struct SRoutes { SRoute r[5]; };

__global__ __launch_bounds__(256) void k_small(SRoutes RR) {
    const SRoute rt = RR.r[blockIdx.y];
    __shared__ hf Ah[4096];
    __shared__ hf Bh[4096];
    __shared__ hf Bl[4096];
    const int tid = threadIdx.x;
    const int n0 = blockIdx.x * 128;
    const int kbeg = blockIdx.z * 128;
    const int lane = tid & 63, wid = tid >> 6;
    const int wm = wid >> 1, wn = wid & 1;
    const int lr = lane & 15, lg = lane >> 4;
    const int srow = tid >> 2, sseg = tid & 3;
    const int wo_ = srow * 32 + (sseg ^ ((srow >> 1) & 3)) * 8;
    const int rsl = (lg ^ ((lr >> 1) & 3)) * 8;
    int ar0 = rt.m0 + srow;      if (ar0 >= rt.M) ar0 = rt.M - 1;
    int ar1 = rt.m0 + 64 + srow; if (ar1 >= rt.M) ar1 = rt.M - 1;
    const bool hasL = rt.Bl != nullptr;
    const int ko = kbeg + sseg * 8;

    f4v acc[4][4];
    f4v zz; zz[0] = 0.f; zz[1] = 0.f; zz[2] = 0.f; zz[3] = 0.f;
#pragma unroll
    for (int a = 0; a < 4; ++a)
#pragma unroll
        for (int b = 0; b < 4; ++b) acc[a][b] = zz;

    h8v va0, va1, vb0, vb1, wb0, wb1;
    auto LOAD = [&](int kk) {
        va0 = *(const h8v*)(rt.A + (size_t)ar0 * KD + ko + kk);
        va1 = *(const h8v*)(rt.A + (size_t)ar1 * KD + ko + kk);
        vb0 = *(const h8v*)(rt.Bh + (size_t)(n0 + srow) * KD + ko + kk);
        vb1 = *(const h8v*)(rt.Bh + (size_t)(n0 + 64 + srow) * KD + ko + kk);
        if (hasL) {
            wb0 = *(const h8v*)(rt.Bl + (size_t)(n0 + srow) * KD + ko + kk);
            wb1 = *(const h8v*)(rt.Bl + (size_t)(n0 + 64 + srow) * KD + ko + kk);
        }
    };
    LOAD(0);
    for (int t = 0; t < 4; ++t) {
        __syncthreads();
        *(h8v*)(Ah + wo_) = va0; *(h8v*)(Ah + 2048 + wo_) = va1;
        *(h8v*)(Bh + wo_) = vb0; *(h8v*)(Bh + 2048 + wo_) = vb1;
        if (hasL) { *(h8v*)(Bl + wo_) = wb0; *(h8v*)(Bl + 2048 + wo_) = wb1; }
        __syncthreads();
        if (t + 1 < 4) LOAD((t + 1) * 32);
        h8v fa[4], fb[4];
#pragma unroll
        for (int x = 0; x < 4; ++x) {
            fa[x] = *(const h8v*)(Ah + (wm * 64 + x * 16 + lr) * 32 + rsl);
            fb[x] = *(const h8v*)(Bh + (wn * 64 + x * 16 + lr) * 32 + rsl);
        }
#pragma unroll
        for (int mi = 0; mi < 4; ++mi)
#pragma unroll
            for (int ni = 0; ni < 4; ++ni)
                acc[mi][ni] = __builtin_amdgcn_mfma_f32_16x16x32_f16(fa[mi], fb[ni], acc[mi][ni], 0, 0, 0);
        if (hasL) {
#pragma unroll
            for (int x = 0; x < 4; ++x)
                fb[x] = *(const h8v*)(Bl + (wn * 64 + x * 16 + lr) * 32 + rsl);
#pragma unroll
            for (int mi = 0; mi < 4; ++mi)
#pragma unroll
                for (int ni = 0; ni < 4; ++ni)
                    acc[mi][ni] = __builtin_amdgcn_mfma_f32_16x16x32_f16(fa[mi], fb[ni], acc[mi][ni], 0, 0, 0);
        }
    }
#pragma unroll
    for (int mi = 0; mi < 4; ++mi)
#pragma unroll
        for (int ni = 0; ni < 4; ++ni)
#pragma unroll
            for (int r = 0; r < 4; ++r) {
                int gr = rt.m0 + wm * 64 + mi * 16 + lg * 4 + r;
                int gc = n0 + wn * 64 + ni * 16 + lr;
                if (gr < rt.M) {
                    float v = acc[mi][ni][r];
                    if (rt.bias && blockIdx.z == 0) v += rt.bias[gc];
                    atomicAdd(rt.C + (size_t)gr * KD + gc, v);
                }
            }
}

// ---------------------------------------------------------------- softmax (rows + cols in one launch)
__global__ void k_softmax_both(const float* __restrict__ adj, float* __restrict__ p,
                               float* __restrict__ q) {
    int b = blockIdx.x;
    if (b < NS) {
        __shared__ float red[256];
        int i = b, j = threadIdx.x;
        float x = adj[i * 256 + j];
        red[j] = x; __syncthreads();
        for (int s = 128; s > 0; s >>= 1) { if (j < s) red[j] = fmaxf(red[j], red[j + s]); __syncthreads(); }
        float mx = red[0]; __syncthreads();
        float e = __expf(x - mx);
        red[j] = e; __syncthreads();
        for (int s = 128; s > 0; s >>= 1) { if (j < s) red[j] += red[j + s]; __syncthreads(); }
        p[i * 256 + j] = e / red[0];
    } else {
        int j = (b - NS) * 4 + (threadIdx.x >> 6);   // 4 cols per block, 1 wave each
        int i = threadIdx.x & 63;
        float x = adj[i * 256 + j];
        float mx = x;
#pragma unroll
        for (int off = 32; off > 0; off >>= 1) mx = fmaxf(mx, __shfl_xor(mx, off));
        float e = __expf(x - mx);
        float s = e;
#pragma unroll
        for (int off = 32; off > 0; off >>= 1) s += __shfl_xor(s, off);
        q[i * 256 + j] = e / s;
    }
}

__global__ void k_build_Gh(const hf* __restrict__ S, const float* __restrict__ aF,
                           const float* __restrict__ p, hf* __restrict__ Gh) {
    __shared__ float pl[256];
    int i = blockIdx.x;
    int k = blockIdx.y * 256 + threadIdx.x;
    pl[threadIdx.x] = p[i * 256 + threadIdx.x];
    __syncthreads();
    const hf* sp = S + (size_t)(i * 256) * KD + k;
    float acc = 0.f;
#pragma unroll 4
    for (int j = 0; j < 256; ++j) {
        float a = aF[(size_t)j * KD + k];
        float s = (float)sp[(size_t)j * KD];
        float g = a * s; g = g > 0.f ? g : 0.f;
        acc += pl[j] * g;
    }
    Gh[(size_t)i * KD + k] = (hf)acc;
}

__global__ void k_build_Go(const hf* __restrict__ S, const float* __restrict__ aF,
                           const float* __restrict__ q, hf* __restrict__ Go) {
    __shared__ float ql[64];
    int j = blockIdx.x;
    int k = blockIdx.y * 256 + threadIdx.x;
    if (threadIdx.x < 64) ql[threadIdx.x] = q[threadIdx.x * 256 + j];
    __syncthreads();
    const hf* sp = S + (size_t)j * KD + k;
    float acc = 0.f;
#pragma unroll 4
    for (int i = 0; i < 64; ++i) {
        float a = aF[(size_t)i * KD + k];
        float s = (float)sp[(size_t)(i * 256) * KD];
        float g = a * s; g = g > 0.f ? g : 0.f;
        acc += ql[i] * g;
    }
    Go[(size_t)j * KD + k] = (hf)acc;
}

__global__ void k_ln_update(float* __restrict__ x, const float* __restrict__ msg,
                            const float* __restrict__ b3, const float* __restrict__ gamma,
                            const float* __restrict__ beta, hf* __restrict__ x16) {
    __shared__ float red[256];
    int r = blockIdx.x, t = threadIdx.x;
    float v[4];
    float s = 0.f;
#pragma unroll
    for (int e = 0; e < 4; ++e) {
        int idx = t + e * 256;
        float mm = msg[(size_t)r * KD + idx] + b3[idx];
        mm = mm > 0.f ? mm : 0.f;
        v[e] = x[(size_t)r * KD + idx] + mm;
        s += v[e];
    }
    red[t] = s; __syncthreads();
    for (int st = 128; st > 0; st >>= 1) { if (t < st) red[t] += red[t + st]; __syncthreads(); }
    float mean = red[0] * (1.f / 1024.f);
    __syncthreads();
    float s2 = 0.f;
#pragma unroll
    for (int e = 0; e < 4; ++e) { float d = v[e] - mean; s2 += d * d; }
    red[t] = s2; __syncthreads();
    for (int st = 128; st > 0; st >>= 1) { if (t < st) red[t] += red[t + st]; __syncthreads(); }
    float var = red[0] * (1.f / 1024.f);
    float rstd = rsqrtf(var + 1e-5f);
#pragma unroll
    for (int e = 0; e < 4; ++e) {
        int idx = t + e * 256;
        float y = (v[e] - mean) * rstd * gamma[idx] + beta[idx];
        x[(size_t)r * KD + idx] = y;
        x16[(size_t)r * KD + idx] = (hf)y;
    }
}

// ---------------------------------------------------------------- launch
extern "C" void kernel_launch(void* const* d_in, const int* in_sizes, int n_in,
                              void* d_out, int out_size, void* d_ws, size_t ws_size,
                              hipStream_t stream) {
    const float* h_in    = (const float*)d_in[0];
    const float* o_in    = (const float*)d_in[1];
    const float* spatial = (const float*)d_in[2];
    const float* att_w1  = (const float*)d_in[3];
    const float* att_b1  = (const float*)d_in[4];
    const float* att_w2  = (const float*)d_in[5];
    const float* att_b2  = (const float*)d_in[6];
    const float* att_w3  = (const float*)d_in[7];
    const float* att_b3  = (const float*)d_in[8];
    const float* s2o_w1  = (const float*)d_in[9];
    const float* s2o_b1  = (const float*)d_in[10];
    const float* s2o_w2  = (const float*)d_in[11];
    const float* s2o_b2  = (const float*)d_in[12];
    const float* s2o_w3  = (const float*)d_in[13];
    const float* s2o_b3  = (const float*)d_in[14];
    const float* o2s_w1  = (const float*)d_in[15];
    const float* o2s_b1  = (const float*)d_in[16];
    const float* o2s_w2  = (const float*)d_in[17];
    const float* o2s_b2  = (const float*)d_in[18];
    const float* o2s_w3  = (const float*)d_in[19];
    const float* o2s_b3  = (const float*)d_in[20];
    const float* adj_w   = (const float*)d_in[21];
    const float* ns_g    = (const float*)d_in[23];
    const float* ns_b    = (const float*)d_in[24];
    const float* no_g    = (const float*)d_in[25];
    const float* no_b    = (const float*)d_in[26];
    // adj_b (d_in[22]) dropped: softmax is shift-invariant.

    char* ws = (char*)d_ws;
    size_t off = 0;
    auto alloc = [&](size_t bytes) -> char* {
        char* pp = ws + off;
        off += (bytes + 255) & ~(size_t)255;
        return pp;
    };
    const size_t PLANE = (size_t)MP * KD * sizeof(hf);     // 32MB
    const size_t WMAT  = (size_t)1024 * 1024 * sizeof(hf); // 2MB
    hf* S_att_h = (hf*)alloc(PLANE);
    hf* S_att_l = (hf*)alloc(PLANE);
    hf* S_o2s   = (hf*)alloc(PLANE);
    hf* S_s2o   = (hf*)alloc(PLANE);
    hf* sp16    = (hf*)alloc(PLANE);
    hf* W2att_h = (hf*)alloc(WMAT); hf* W2att_l = (hf*)alloc(WMAT);
    hf* W2o2s   = (hf*)alloc(WMAT);
    hf* W2s2o   = (hf*)alloc(WMAT);
    hf* W1ah_h  = (hf*)alloc(WMAT); hf* W1ah_l  = (hf*)alloc(WMAT);
    hf* W1ao_h  = (hf*)alloc(WMAT); hf* W1ao_l  = (hf*)alloc(WMAT);
    hf* W1o2s   = (hf*)alloc(WMAT);
    hf* W1s2o   = (hf*)alloc(WMAT);
    hf* W3a_h   = (hf*)alloc(WMAT); hf* W3a_l   = (hf*)alloc(WMAT);
    hf* W3o     = (hf*)alloc(WMAT);
    hf* W3s     = (hf*)alloc(WMAT);
    float* b2cat = (float*)alloc(3072 * 4);
    float* b3a   = (float*)alloc(1024 * 4);
    float* b3o   = (float*)alloc(1024 * 4);
    float* b3s   = (float*)alloc(1024 * 4);
    // contiguous zero-region (one memset per iteration)
    float* fc1h = (float*)alloc((size_t)NS * KD * 4);
    float* fc1o = (float*)alloc((size_t)NO * KD * 4);
    float* aO2S = (float*)alloc((size_t)NO * KD * 4);
    float* aS2O = (float*)alloc((size_t)NS * KD * 4);
    float* msgh = (float*)alloc((size_t)NS * KD * 4);
    float* msgo = (float*)alloc((size_t)NO * KD * 4);
    float* adjv = (float*)alloc((size_t)MP * 4);
    char* zend_ = (char*)(adjv + MP);
    size_t zlen = (size_t)(zend_ - (char*)fc1h);
    float* pbuf = (float*)alloc((size_t)MP * 4);
    float* qbuf = (float*)alloc((size_t)MP * 4);
    hf* h16 = (hf*)alloc((size_t)NS * KD * sizeof(hf));
    hf* o16 = (hf*)alloc((size_t)NO * KD * sizeof(hf));
    hf* Gh  = (hf*)alloc((size_t)NS * KD * sizeof(hf));
    hf* Go  = (hf*)alloc((size_t)NO * KD * sizeof(hf));

    float* hbuf = (float*)d_out;             // [64,1024]
    float* obuf = (float*)d_out + NS * KD;   // [256,1024]

    // ---- prep (iteration-invariant) ----
    k_pack16<<<dim3(MP * KD / 8 / 256), 256, 0, stream>>>(spatial, sp16, MP * KD / 8);
    {
        RoRs R;
        R.r[0] = { att_w2, W2att_h, W2att_l, 1024, 0 };
        R.r[1] = { o2s_w2, W2o2s, nullptr, 1024, 0 };
        R.r[2] = { s2o_w2, W2s2o, nullptr, 1024, 0 };
        R.r[3] = { att_w1, W1ah_h, W1ah_l, 2048, 0 };
        R.r[4] = { att_w1, W1ao_h, W1ao_l, 2048, 1024 };
        R.r[5] = { o2s_w1, W1o2s, nullptr, 1024, 0 };
        R.r[6] = { s2o_w1, W1s2o, nullptr, 1024, 0 };
        k_reorder16b<<<dim3(16, 16, 7), 256, 0, stream>>>(R);
    }
    {
        TrRs T;
        T.r[0] = { att_w3, W3a_h, W3a_l };
        T.r[1] = { o2s_w3, W3o, nullptr };
        T.r[2] = { s2o_w3, W3s, nullptr };
        k_transpose16b<<<dim3(16, 16, 3), 256, 0, stream>>>(T);
    }
    k_prep_bc<<<dim3(4), 256, 0, stream>>>(att_b2, o2s_b2, s2o_b2, att_b3, o2s_b3, s2o_b3,
                                           b2cat, b3a, b3o, b3s);
    k_init_ho<<<dim3(1280), 256, 0, stream>>>(h_in, o_in, (float*)d_out, h16, o16);
    k_prep_gemm<<<dim3(24, 128), 256, 0, stream>>>(sp16, W2att_h, W2att_l, W2o2s, W2s2o,
                                                   b2cat, S_att_h, S_att_l, S_o2s, S_s2o);

    for (int it = 0; it < 2; ++it) {
        hipMemsetAsync(fc1h, 0, zlen, stream);
        // fc1h = h@W1ah(+lo)+b1 ; fc1o = o@W1ao(+lo) ; aO2S = o@W1o2s+b1
        {
            SRoutes R;
            R.r[0] = { h16, W1ah_h, W1ah_l, fc1h, att_b1, 0,   NS };
            R.r[1] = { o16, W1ao_h, W1ao_l, fc1o, nullptr, 0,   NO };
            R.r[2] = { o16, W1ao_h, W1ao_l, fc1o, nullptr, 128, NO };
            R.r[3] = { o16, W1o2s,  nullptr, aO2S, o2s_b1, 0,   NO };
            R.r[4] = { o16, W1o2s,  nullptr, aO2S, o2s_b1, 128, NO };
            k_small<<<dim3(8, 5, 8), 256, 0, stream>>>(R);
        }
        k_adj_gemm<<<dim3(4, 128), 256, 0, stream>>>(S_att_h, S_att_l, fc1h, fc1o,
                                                     W3a_h, W3a_l, b3a, adj_w, adjv);
        k_softmax_both<<<dim3(NS + NO / 4), 256, 0, stream>>>(adjv, pbuf, qbuf);
        // h update
        k_build_Gh<<<dim3(NS, 4), 256, 0, stream>>>(S_o2s, aO2S, pbuf, Gh);
        {
            SRoutes R;
            R.r[0] = { Gh, W3o, nullptr, msgh, nullptr, 0, NS };
            k_small<<<dim3(8, 1, 8), 256, 0, stream>>>(R);
        }
        k_ln_update<<<dim3(NS), 256, 0, stream>>>(hbuf, msgh, b3o, ns_g, ns_b, h16);
        // o update (uses updated h)
        {
            SRoutes R;
            R.r[0] = { h16, W1s2o, nullptr, aS2O, s2o_b1, 0, NS };
            k_small<<<dim3(8, 1, 8), 256, 0, stream>>>(R);
        }
        k_build_Go<<<dim3(NO, 4), 256, 0, stream>>>(S_s2o, aS2O, qbuf, Go);
        {
            SRoutes R;
            R.r[0] = { Go, W3s, nullptr, msgo, nullptr, 0,   NO };
            R.r[1] = { Go, W3s, nullptr, msgo, nullptr, 128, NO };
            k_small<<<dim3(8, 2, 8), 256, 0, stream>>>(R);
        }
        k_ln_update<<<dim3(NO), 256, 0, stream>>>(obuf, msgo, b3s, no_g, no_b, o16);
    }
    (void)in_sizes; (void)n_in; (void)out_size; (void)ws_size;
}